// Round 10
// baseline (489.559 us; speedup 1.0000x reference)
//
#include <hip/hip_runtime.h>
#include <hip/hip_bf16.h>

// Inputs fp32, output fp32 (proven). Intermediates bf16 in ws.
#define HH    768
#define NHEAD 12
#define HDIM  64
#define BB    4
#define SS    2048
#define MM    (BB*SS)     // 8192 rows
#define NDIMS 5
#define WEL   (HH*HH)     // 589824 elements per weight matrix
#define LOG2E 1.44269504088896f
#define QSCALE 0.180336881f   // 0.125 * log2e

typedef unsigned short u16;
typedef __attribute__((ext_vector_type(8))) short short8;     // 8 bf16 (4 VGPRs)
typedef __attribute__((ext_vector_type(4))) float floatx4;    // 16x16 MFMA C/D
typedef __attribute__((ext_vector_type(16))) float floatx16;  // 32x32 MFMA C/D

__device__ __forceinline__ float bf2f(u16 u) {
    return __uint_as_float(((unsigned int)u) << 16);
}
__device__ __forceinline__ u16 f2bf(float f) {
    unsigned int x = __float_as_uint(f);
    unsigned int r = (x + 0x7fffu + ((x >> 16) & 1u)) >> 16;
    return (u16)r;
}
__device__ __forceinline__ unsigned int pack_bf16x2(float a, float b) {
    float2 f2 = make_float2(a, b);
    __hip_bfloat162 h2 = __float22bfloat162_rn(f2);
    return *reinterpret_cast<unsigned int*>(&h2);
}

// fp32 -> bf16, 8 elements/thread
__global__ __launch_bounds__(256) void f32_to_bf16(
    const float* __restrict__ in, u16* __restrict__ out, int n8)
{
    int i = blockIdx.x * 256 + threadIdx.x;
    if (i >= n8) return;
    float4 a = ((const float4*)in)[i*2];
    float4 b = ((const float4*)in)[i*2 + 1];
    ushort4 lo, hi;
    lo.x = f2bf(a.x); lo.y = f2bf(a.y); lo.z = f2bf(a.z); lo.w = f2bf(a.w);
    hi.x = f2bf(b.x); hi.y = f2bf(b.y); hi.z = f2bf(b.z); hi.w = f2bf(b.w);
    ((ushort4*)out)[i*2]     = lo;
    ((ushort4*)out)[i*2 + 1] = hi;
}

// Convert 4 weight matrices fp32->bf16 in one launch -> contiguous 3072x768 bf16.
__global__ __launch_bounds__(256) void w_cvt4(
    const float* __restrict__ W0, const float* __restrict__ W1,
    const float* __restrict__ W2, const float* __restrict__ W3,
    u16* __restrict__ out)
{
    const float* src = (blockIdx.y == 0) ? W0 : (blockIdx.y == 1) ? W1
                     : (blockIdx.y == 2) ? W2 : W3;
    u16* dst = out + (size_t)blockIdx.y * WEL;
    int i = blockIdx.x * 256 + threadIdx.x;
    float4 a = ((const float4*)src)[i*2];
    float4 b = ((const float4*)src)[i*2 + 1];
    ushort4 lo, hi;
    lo.x = f2bf(a.x); lo.y = f2bf(a.y); lo.z = f2bf(a.z); lo.w = f2bf(a.w);
    hi.x = f2bf(b.x); hi.y = f2bf(b.y); hi.z = f2bf(b.z); hi.w = f2bf(b.w);
    ((ushort4*)dst)[i*2]     = lo;
    ((ushort4*)dst)[i*2 + 1] = hi;
}

// ---- 32x32x16 MFMA GEMM, BK=64, register-prefetch double buffer.
// out(local col space): outL[(i0+row)*HH + col] = sum_k Xb[i0+row,k]*Wrows[col,k] + biasL[col].
// Wrows points at the block's first weight row; biasL/outL are pre-offset by the
// block's column base. 128x128 block, 4 waves (2x2), 64x64/wave.
// A/B: idx=lane&31, k=(lane>>5)*8+j (HW-verified r9). D: col=lane&31, row=(reg&3)+8*(reg>>2)+4*(lane>>5).
__device__ __forceinline__ void gemm64_body(
    const u16* __restrict__ Xb, const u16* __restrict__ Wrows,
    const float* __restrict__ biasL, u16* __restrict__ outL, int i0)
{
    __shared__ u16 Xs[128][72];   // stride 72 u16 = 144B
    __shared__ u16 Wt[128][72];
    const int t = threadIdx.x;
    const int w = t >> 6, lane = t & 63;
    const int wy = w >> 1, wx = w & 1;
    const int m = lane & 31, hh = lane >> 5;
    const int srow = t >> 1, sh2 = (t & 1) * 32;   // staging: row, u16 base 0/32

    floatx16 acc[2][2];
    #pragma unroll
    for (int am = 0; am < 2; ++am)
        #pragma unroll
        for (int bn = 0; bn < 2; ++bn)
            #pragma unroll
            for (int r = 0; r < 16; ++r) acc[am][bn][r] = 0.f;

    const u16* xp = Xb + (size_t)(i0 + srow)*HH + sh2;
    const u16* wp = Wrows + (size_t)srow*HH + sh2;

    uint4 xv[4], wv[4];
    #pragma unroll
    for (int j = 0; j < 4; ++j) {
        xv[j] = *(const uint4*)(xp + j*8);
        wv[j] = *(const uint4*)(wp + j*8);
    }

    for (int k0 = 0; k0 < HH; k0 += 64) {
        __syncthreads();   // previous iter's frag reads done
        #pragma unroll
        for (int j = 0; j < 4; ++j) {
            *(uint4*)&Xs[srow][sh2 + j*8] = xv[j];
            *(uint4*)&Wt[srow][sh2 + j*8] = wv[j];
        }
        __syncthreads();
        if (k0 + 64 < HH) {   // prefetch next tile; latency overlaps MFMA below
            #pragma unroll
            for (int j = 0; j < 4; ++j) {
                xv[j] = *(const uint4*)(xp + k0 + 64 + j*8);
                wv[j] = *(const uint4*)(wp + k0 + 64 + j*8);
            }
        }
        #pragma unroll
        for (int kh = 0; kh < 4; ++kh) {
            short8 af[2], bf[2];
            af[0] = *(const short8*)&Xs[wy*64 + m][kh*16 + hh*8];
            af[1] = *(const short8*)&Xs[wy*64 + 32 + m][kh*16 + hh*8];
            bf[0] = *(const short8*)&Wt[wx*64 + m][kh*16 + hh*8];
            bf[1] = *(const short8*)&Wt[wx*64 + 32 + m][kh*16 + hh*8];
            #pragma unroll
            for (int am = 0; am < 2; ++am)
                #pragma unroll
                for (int bn = 0; bn < 2; ++bn)
                    acc[am][bn] = __builtin_amdgcn_mfma_f32_32x32x16_bf16(
                        af[am], bf[bn], acc[am][bn], 0, 0, 0);
        }
    }

    float bb[2];
    #pragma unroll
    for (int bn = 0; bn < 2; ++bn) bb[bn] = biasL[wx*64 + bn*32 + m];
    #pragma unroll
    for (int am = 0; am < 2; ++am)
        #pragma unroll
        for (int bn = 0; bn < 2; ++bn)
            #pragma unroll
            for (int r = 0; r < 16; ++r) {
                int row = i0 + wy*64 + am*32 + (r & 3) + 8*(r >> 2) + 4*hh;
                outL[(size_t)row*HH + wx*64 + bn*32 + m] = f2bf(acc[am][bn][r] + bb[bn]);
            }
}

// Fused QKV: wb is a contiguous 2304x768 bf16 matrix (Wq;Wk;Wv). N=2304, BN=128;
// 768%128==0 so each block's columns land in exactly one of q/k/v.
__global__ __launch_bounds__(256) void gemm64_qkv(
    const u16* __restrict__ Xb, const u16* __restrict__ Wb3,
    const float* __restrict__ bq, const float* __restrict__ bk, const float* __restrict__ bv,
    u16* __restrict__ oq, u16* __restrict__ ok, u16* __restrict__ ov)
{
    const int j0 = blockIdx.x * 128;
    const int sel = j0 / HH;
    const int lj = j0 - sel * HH;
    const float* bias = (sel == 0) ? bq : (sel == 1) ? bk : bv;
    u16* out = (sel == 0) ? oq : (sel == 1) ? ok : ov;
    gemm64_body(Xb, Wb3 + (size_t)j0 * HH, bias + lj, out + lj, blockIdx.y * 128);
}

__global__ __launch_bounds__(256) void gemm64_single(
    const u16* __restrict__ Xb, const u16* __restrict__ Wb,
    const float* __restrict__ bias, u16* __restrict__ out)
{
    const int j0 = blockIdx.x * 128;
    gemm64_body(Xb, Wb + (size_t)j0 * HH, bias + j0, out + j0, blockIdx.y * 128);
}

// Fallback (small ws): W fp32, cvt during staging — round-6 proven 16x16x32 kernel.
__global__ __launch_bounds__(256) void gemm_mfma_nt(
    const u16* __restrict__ Xb, const float* __restrict__ W,
    const float* __restrict__ bias, u16* __restrict__ out)
{
    __shared__ u16 Xs[128][40];
    __shared__ u16 Wt[64][40];
    const int t = threadIdx.x;
    const int w = t >> 6, lane = t & 63;
    const int c = lane & 15, qd = lane >> 4;
    const int i0 = blockIdx.y * 128, j0 = blockIdx.x * 64;
    const int xrow = t >> 1, xoff = (t & 1) * 16;
    const int wn = t >> 2, woff = (t & 3) * 8;

    floatx4 acc[2][4];
    #pragma unroll
    for (int mt = 0; mt < 2; ++mt)
        #pragma unroll
        for (int nt = 0; nt < 4; ++nt) acc[mt][nt] = (floatx4){0.f,0.f,0.f,0.f};

    for (int k0 = 0; k0 < HH; k0 += 32) {
        uint4 xa  = *(const uint4*)(Xb + (size_t)(i0 + xrow)*HH + k0 + xoff);
        uint4 xb2 = *(const uint4*)(Xb + (size_t)(i0 + xrow)*HH + k0 + xoff + 8);
        float4 wa = *(const float4*)(W + (size_t)(j0 + wn)*HH + k0 + woff);
        float4 wb = *(const float4*)(W + (size_t)(j0 + wn)*HH + k0 + woff + 4);
        __syncthreads();
        *(uint4*)&Xs[xrow][xoff]     = xa;
        *(uint4*)&Xs[xrow][xoff + 8] = xb2;
        ushort4 w0, w1;
        w0.x = f2bf(wa.x); w0.y = f2bf(wa.y); w0.z = f2bf(wa.z); w0.w = f2bf(wa.w);
        w1.x = f2bf(wb.x); w1.y = f2bf(wb.y); w1.z = f2bf(wb.z); w1.w = f2bf(wb.w);
        *(ushort4*)&Wt[wn][woff]     = w0;
        *(ushort4*)&Wt[wn][woff + 4] = w1;
        __syncthreads();

        short8 a0 = *(const short8*)&Xs[w*32 + c][qd*8];
        short8 a1 = *(const short8*)&Xs[w*32 + 16 + c][qd*8];
        #pragma unroll
        for (int nt = 0; nt < 4; ++nt) {
            short8 bfr = *(const short8*)&Wt[nt*16 + c][qd*8];
            acc[0][nt] = __builtin_amdgcn_mfma_f32_16x16x32_bf16(a0, bfr, acc[0][nt], 0, 0, 0);
            acc[1][nt] = __builtin_amdgcn_mfma_f32_16x16x32_bf16(a1, bfr, acc[1][nt], 0, 0, 0);
        }
    }

    float bv[4];
    #pragma unroll
    for (int nt = 0; nt < 4; ++nt) bv[nt] = bias[j0 + nt*16 + c];
    #pragma unroll
    for (int mt = 0; mt < 2; ++mt)
        #pragma unroll
        for (int nt = 0; nt < 4; ++nt)
            #pragma unroll
            for (int r = 0; r < 4; ++r)
                out[(size_t)(i0 + w*32 + mt*16 + qd*4 + r)*HH + j0 + nt*16 + c] =
                    f2bf(acc[mt][nt][r] + bv[nt]);
}

// MFMA flash attention — unchanged from round 9 (verified).
__global__ __launch_bounds__(256, 3) void attn_mfma(
    const u16* __restrict__ Q, const u16* __restrict__ K, const u16* __restrict__ V,
    const float* __restrict__ dim_biases, const int* __restrict__ mask,
    const int* __restrict__ dim_idx_p, u16* __restrict__ ctx)
{
    __shared__ u16 Ks[64][72];           // [key][d]
    __shared__ unsigned int Vt2[64][36]; // [d][keypair] packed 2 keys/uint
    __shared__ u16 Pt[4][2][16][72];     // [wave][group][q][key]  wave-private
    __shared__ float madd[64];

    const int t = threadIdx.x;
    const int w = t >> 6, lane = t & 63;
    const int c = lane & 15, qd = lane >> 4;
    const int b = blockIdx.z, h = blockIdx.y;
    const int q0 = blockIdx.x * 128;

    const int didx = *dim_idx_p;
    const float db2 = ((didx < NDIMS) ? dim_biases[didx*NHEAD + h] : 0.f) * LOG2E;

    short8 ones;
    #pragma unroll
    for (int j = 0; j < 8; ++j) ones[j] = (short)0x3F80;   // bf16 1.0

    short8 qf[2][2];
    #pragma unroll
    for (int g = 0; g < 2; ++g) {
        const u16* qsrc = Q + ((size_t)(b*SS + q0 + w*32 + g*16 + c))*HH + h*HDIM;
        #pragma unroll
        for (int kc = 0; kc < 2; ++kc) {
            ushort4 u0 = *(const ushort4*)(qsrc + kc*32 + qd*8);
            ushort4 u1 = *(const ushort4*)(qsrc + kc*32 + qd*8 + 4);
            const u16 uu[8] = {u0.x,u0.y,u0.z,u0.w,u1.x,u1.y,u1.z,u1.w};
            #pragma unroll
            for (int j = 0; j < 8; ++j)
                qf[g][kc][j] = (short)f2bf(bf2f(uu[j]) * QSCALE);
        }
    }

    floatx4 o[2][4], lacc[2];
    #pragma unroll
    for (int g = 0; g < 2; ++g) {
        lacc[g] = (floatx4){0.f,0.f,0.f,0.f};
        #pragma unroll
        for (int dt = 0; dt < 4; ++dt) o[g][dt] = (floatx4){0.f,0.f,0.f,0.f};
    }

    const int skey = t >> 2, sdp = (t & 3) * 16;
    const int vkp = t & 31, vdg = (t >> 5) * 8;

    for (int kt = 0; kt < SS/64; ++kt) {
        __syncthreads();
        {
            const u16* ksrc = K + ((size_t)(b*SS + kt*64 + skey))*HH + h*HDIM + sdp;
            *(uint4*)&Ks[skey][sdp]     = *(const uint4*)ksrc;
            *(uint4*)&Ks[skey][sdp + 8] = *(const uint4*)(ksrc + 8);
            const u16* va = V + ((size_t)(b*SS + kt*64 + 2*vkp))*HH + h*HDIM + vdg;
            const u16* vb = va + HH;
            ushort4 a0 = *(const ushort4*)va;
            ushort4 a1 = *(const ushort4*)(va + 4);
            ushort4 b0 = *(const ushort4*)vb;
            ushort4 b1 = *(const ushort4*)(vb + 4);
            const u16 aa[8] = {a0.x,a0.y,a0.z,a0.w,a1.x,a1.y,a1.z,a1.w};
            const u16 bb[8] = {b0.x,b0.y,b0.z,b0.w,b1.x,b1.y,b1.z,b1.w};
            #pragma unroll
            for (int i = 0; i < 8; ++i)
                Vt2[vdg + i][vkp] = (unsigned int)aa[i] | ((unsigned int)bb[i] << 16);
            if (t < 64)
                madd[t] = (mask[(size_t)b*SS + kt*64 + t] != 0) ? db2 : -1e30f;
        }
        __syncthreads();

        floatx4 z[2][4];
        {
            short8 ka[4][2];
            #pragma unroll
            for (int mt = 0; mt < 4; ++mt) {
                ka[mt][0] = *(const short8*)&Ks[mt*16 + c][qd*8];
                ka[mt][1] = *(const short8*)&Ks[mt*16 + c][32 + qd*8];
            }
            #pragma unroll
            for (int g = 0; g < 2; ++g)
                #pragma unroll
                for (int mt = 0; mt < 4; ++mt) {
                    floatx4 zz = __builtin_amdgcn_mfma_f32_16x16x32_bf16(ka[mt][0], qf[g][0], (floatx4){0.f,0.f,0.f,0.f}, 0, 0, 0);
                    z[g][mt] = __builtin_amdgcn_mfma_f32_16x16x32_bf16(ka[mt][1], qf[g][1], zz, 0, 0, 0);
                }
        }

        #pragma unroll
        for (int g = 0; g < 2; ++g) {
            #pragma unroll
            for (int mt = 0; mt < 4; ++mt) {
                unsigned int pk[2];
                #pragma unroll
                for (int half = 0; half < 2; ++half) {
                    float p0 = __builtin_amdgcn_exp2f(z[g][mt][half*2]     + madd[mt*16 + qd*4 + half*2]);
                    float p1 = __builtin_amdgcn_exp2f(z[g][mt][half*2 + 1] + madd[mt*16 + qd*4 + half*2 + 1]);
                    pk[half] = pack_bf16x2(p0, p1);
                }
                *(uint2*)&Pt[w][g][c][mt*16 + qd*4] = make_uint2(pk[0], pk[1]);
            }
        }

        {
            short8 vt[2][4];
            #pragma unroll
            for (int kc = 0; kc < 2; ++kc)
                #pragma unroll
                for (int dt = 0; dt < 4; ++dt)
                    vt[kc][dt] = *(const short8*)&Vt2[dt*16 + c][kc*16 + qd*4];
            #pragma unroll
            for (int g = 0; g < 2; ++g)
                #pragma unroll
                for (int kc = 0; kc < 2; ++kc) {
                    short8 ap = *(const short8*)&Pt[w][g][c][kc*32 + qd*8];
                    lacc[g] = __builtin_amdgcn_mfma_f32_16x16x32_bf16(ap, ones, lacc[g], 0, 0, 0);
                    #pragma unroll
                    for (int dt = 0; dt < 4; ++dt)
                        o[g][dt] = __builtin_amdgcn_mfma_f32_16x16x32_bf16(ap, vt[kc][dt], o[g][dt], 0, 0, 0);
                }
        }
    }

    #pragma unroll
    for (int g = 0; g < 2; ++g) {
        #pragma unroll
        for (int r = 0; r < 4; ++r) {
            float lr = lacc[g][r];
            float inv = (lr > 0.f) ? 1.f / lr : 0.f;
            u16* dst = ctx + ((size_t)(b*SS + q0 + w*32 + g*16 + qd*4 + r))*HH + h*HDIM + c;
            #pragma unroll
            for (int dt = 0; dt < 4; ++dt)
                dst[dt*16] = f2bf(o[g][dt][r] * inv);
        }
    }
}

// Wave-per-row LN: 4 rows/block, lane handles 12 contiguous elements.
__global__ __launch_bounds__(256) void add_ln_wave(
    const u16* __restrict__ proj, const float* __restrict__ resid,
    const float* __restrict__ gamma, const float* __restrict__ beta,
    float* __restrict__ out)
{
    const int t = threadIdx.x, w = t >> 6, lane = t & 63;
    const int row = blockIdx.x * 4 + w;
    const size_t base = (size_t)row * HH + lane * 12;
    const int gbase = lane * 12;

    float x[12];
    #pragma unroll
    for (int j = 0; j < 3; ++j) {
        ushort4 p = *(const ushort4*)(proj + base + j*4);
        float4  r = *(const float4*)(resid + base + j*4);
        x[j*4+0] = bf2f(p.x) + r.x;
        x[j*4+1] = bf2f(p.y) + r.y;
        x[j*4+2] = bf2f(p.z) + r.z;
        x[j*4+3] = bf2f(p.w) + r.w;
    }
    float s = 0.f, ss = 0.f;
    #pragma unroll
    for (int j = 0; j < 12; ++j) { s += x[j]; ss += x[j]*x[j]; }
    #pragma unroll
    for (int off = 1; off < 64; off <<= 1) {
        s  += __shfl_xor(s, off);
        ss += __shfl_xor(ss, off);
    }
    float mean = s * (1.f/768.f);
    float var  = ss * (1.f/768.f) - mean*mean;
    float rstd = rsqrtf(fmaxf(var, 0.f) + 1e-5f);
    #pragma unroll
    for (int j = 0; j < 3; ++j) {
        float4 g = *(const float4*)(gamma + gbase + j*4);
        float4 bt = *(const float4*)(beta + gbase + j*4);
        float4 y;
        y.x = (x[j*4+0]-mean)*rstd*g.x + bt.x;
        y.y = (x[j*4+1]-mean)*rstd*g.y + bt.y;
        y.z = (x[j*4+2]-mean)*rstd*g.z + bt.z;
        y.w = (x[j*4+3]-mean)*rstd*g.w + bt.w;
        *(float4*)(out + base + j*4) = y;
    }
}

extern "C" void kernel_launch(void* const* d_in, const int* in_sizes, int n_in,
                              void* d_out, int out_size, void* d_ws, size_t ws_size,
                              hipStream_t stream)
{
    (void)in_sizes; (void)n_in; (void)out_size;
    const float* x    = (const float*)d_in[0];
    const float* Wq   = (const float*)d_in[1];
    const float* bq   = (const float*)d_in[2];
    const float* Wk   = (const float*)d_in[3];
    const float* bk   = (const float*)d_in[4];
    const float* Wv   = (const float*)d_in[5];
    const float* bv   = (const float*)d_in[6];
    const float* Wo   = (const float*)d_in[7];
    const float* bo   = (const float*)d_in[8];
    const float* dimb = (const float*)d_in[9];
    const float* gam  = (const float*)d_in[10];
    const float* bet  = (const float*)d_in[11];
    const int* mask   = (const int*)d_in[12];
    const int* didx   = (const int*)d_in[13];

    const size_t N = (size_t)MM * HH;            // 6,291,456 elements
    if (ws_size < 4 * N * sizeof(u16)) return;   // 50.3 MB, proven
    u16* ws = (u16*)d_ws;
    u16* q    = ws;          // slot0: q, later proj
    u16* kbuf = ws + N;      // slot1
    u16* vbuf = ws + 2*N;    // slot2
    u16* slot3 = ws + 3*N;   // xb during QKV GEMMs, then ctx
    u16* xb   = slot3;
    u16* ctx  = slot3;
    u16* proj = q;

    const bool bigws = ws_size >= (4 * N + 4 * (size_t)WEL) * sizeof(u16);  // +4.7 MB
    u16* wb = ws + 4 * N;    // bf16 weights, contiguous (Wq;Wk;Wv;Wo) = 3072x768

    f32_to_bf16<<<(int)(N/8/256), 256, 0, stream>>>(x, xb, (int)(N/8));
    if (bigws) {
        w_cvt4<<<dim3(WEL/8/256, 4), 256, 0, stream>>>(Wq, Wk, Wv, Wo, wb);
        gemm64_qkv<<<dim3(3*HH/128, MM/128), 256, 0, stream>>>(
            xb, wb, bq, bk, bv, q, kbuf, vbuf);
    } else {
        dim3 gg(HH/64, MM/128);
        gemm_mfma_nt<<<gg, 256, 0, stream>>>(xb, Wq, bq, q);
        gemm_mfma_nt<<<gg, 256, 0, stream>>>(xb, Wk, bk, kbuf);
        gemm_mfma_nt<<<gg, 256, 0, stream>>>(xb, Wv, bv, vbuf);
    }
    attn_mfma<<<dim3(SS/128, NHEAD, BB), 256, 0, stream>>>(q, kbuf, vbuf, dimb, mask, didx, ctx);
    if (bigws) gemm64_single<<<dim3(HH/128, MM/128), 256, 0, stream>>>(ctx, wb + 3*WEL, bo, proj);
    else {
        dim3 gg(HH/64, MM/128);
        gemm_mfma_nt<<<gg, 256, 0, stream>>>(ctx, Wo, bo, proj);
    }
    add_ln_wave<<<MM/4, 256, 0, stream>>>(proj, x, gam, bet, (float*)d_out);
}

// Round 11
// 255.568 us; speedup vs baseline: 1.9156x; 1.9156x over previous
//
#include <hip/hip_runtime.h>
#include <hip/hip_bf16.h>

// Inputs fp32, output fp32 (proven). Intermediates bf16 in ws.
#define HH    768
#define NHEAD 12
#define HDIM  64
#define BB    4
#define SS    2048
#define MM    (BB*SS)     // 8192 rows
#define NDIMS 5
#define WEL   (HH*HH)     // 589824 elements per weight matrix
#define LOG2E 1.44269504088896f
#define QSCALE 0.180336881f   // 0.125 * log2e

typedef unsigned short u16;
typedef __attribute__((ext_vector_type(8))) short short8;     // 8 bf16 (4 VGPRs)
typedef __attribute__((ext_vector_type(4))) float floatx4;    // 16x16 MFMA C/D
typedef __attribute__((ext_vector_type(16))) float floatx16;  // 32x32 MFMA C/D

__device__ __forceinline__ float bf2f(u16 u) {
    return __uint_as_float(((unsigned int)u) << 16);
}
__device__ __forceinline__ u16 f2bf(float f) {
    unsigned int x = __float_as_uint(f);
    unsigned int r = (x + 0x7fffu + ((x >> 16) & 1u)) >> 16;
    return (u16)r;
}
__device__ __forceinline__ unsigned int pack_bf16x2(float a, float b) {
    float2 f2 = make_float2(a, b);
    __hip_bfloat162 h2 = __float22bfloat162_rn(f2);
    return *reinterpret_cast<unsigned int*>(&h2);
}
// async global->LDS, 16 B per lane; LDS dest = wave-uniform base + lane*16
__device__ __forceinline__ void gld16(const u16* g, u16* l) {
    __builtin_amdgcn_global_load_lds(
        (const __attribute__((address_space(1))) unsigned int*)g,
        (__attribute__((address_space(3))) unsigned int*)l, 16, 0, 0);
}

// fp32 -> bf16, 8 elements/thread
__global__ __launch_bounds__(256) void f32_to_bf16(
    const float* __restrict__ in, u16* __restrict__ out, int n8)
{
    int i = blockIdx.x * 256 + threadIdx.x;
    if (i >= n8) return;
    float4 a = ((const float4*)in)[i*2];
    float4 b = ((const float4*)in)[i*2 + 1];
    ushort4 lo, hi;
    lo.x = f2bf(a.x); lo.y = f2bf(a.y); lo.z = f2bf(a.z); lo.w = f2bf(a.w);
    hi.x = f2bf(b.x); hi.y = f2bf(b.y); hi.z = f2bf(b.z); hi.w = f2bf(b.w);
    ((ushort4*)out)[i*2]     = lo;
    ((ushort4*)out)[i*2 + 1] = hi;
}

// Convert 4 weight matrices fp32->bf16 -> contiguous 3072x768 bf16.
__global__ __launch_bounds__(256) void w_cvt4(
    const float* __restrict__ W0, const float* __restrict__ W1,
    const float* __restrict__ W2, const float* __restrict__ W3,
    u16* __restrict__ out)
{
    const float* src = (blockIdx.y == 0) ? W0 : (blockIdx.y == 1) ? W1
                     : (blockIdx.y == 2) ? W2 : W3;
    u16* dst = out + (size_t)blockIdx.y * WEL;
    int i = blockIdx.x * 256 + threadIdx.x;
    float4 a = ((const float4*)src)[i*2];
    float4 b = ((const float4*)src)[i*2 + 1];
    ushort4 lo, hi;
    lo.x = f2bf(a.x); lo.y = f2bf(a.y); lo.z = f2bf(a.z); lo.w = f2bf(a.w);
    hi.x = f2bf(b.x); hi.y = f2bf(b.y); hi.z = f2bf(b.z); hi.w = f2bf(b.w);
    ((ushort4*)dst)[i*2]     = lo;
    ((ushort4*)dst)[i*2 + 1] = hi;
}

// ---- m97-style GEMM: 128x128 block, BK=64, global_load_lds staging,
// XOR-swizzled LDS (row = 8 chunks of 16B; chunk c stored at c^(row&7)).
// 4 waves (2x2), 64x64/wave via 32x32x16 MFMA.
// A/B frag: idx=lane&31, k=(lane>>5)*8+j. D: col=lane&31, row=(reg&3)+8*(reg>>2)+4*(lane>>5).
__device__ __forceinline__ void gemm_gld_body(
    const u16* __restrict__ Xb, const u16* __restrict__ Wrows,
    const float* __restrict__ biasL, u16* __restrict__ outL, int i0)
{
    __shared__ u16 Xs[128][64];   // 16 KB, row = 128 B, swizzled chunks
    __shared__ u16 Ws[128][64];
    const int t = threadIdx.x;
    const int w = t >> 6, lane = t & 63;
    const int wy = w >> 1, wx = w & 1;
    const int m = lane & 31, hh = lane >> 5;

    // staging: wave w, instr j covers rows w*32+j*8 .. +8 (8 rows x 8 chunks).
    // lane i -> row grow=i>>3, LDS chunk i&7, global chunk cg=(i&7)^(i>>3).
    const int grow = lane >> 3;
    const int cg   = (lane & 7) ^ grow;

    floatx16 acc[2][2];
    #pragma unroll
    for (int am = 0; am < 2; ++am)
        #pragma unroll
        for (int bn = 0; bn < 2; ++bn)
            #pragma unroll
            for (int r = 0; r < 16; ++r) acc[am][bn][r] = 0.f;

    for (int k0 = 0; k0 < HH; k0 += 64) {
        __syncthreads();   // previous iter's frag reads complete
        #pragma unroll
        for (int j = 0; j < 4; ++j) {
            const int r = w*32 + j*8;   // row base for this instr
            gld16(Xb    + (size_t)(i0 + r + grow)*HH + k0 + cg*8, &Xs[r][0]);
            gld16(Wrows + (size_t)(r + grow)*HH      + k0 + cg*8, &Ws[r][0]);
        }
        __syncthreads();   // drains vmcnt before barrier (compiler-inserted)

        #pragma unroll
        for (int kh = 0; kh < 4; ++kh) {
            const int ch = kh*2 + hh;   // logical chunk for this k-slice
            short8 af[2], bf[2];
            #pragma unroll
            for (int am = 0; am < 2; ++am) {
                const int row = wy*64 + am*32 + m;
                af[am] = *(const short8*)&Xs[row][(ch ^ (m & 7))*8];
            }
            #pragma unroll
            for (int bn = 0; bn < 2; ++bn) {
                const int row = wx*64 + bn*32 + m;
                bf[bn] = *(const short8*)&Ws[row][(ch ^ (m & 7))*8];
            }
            #pragma unroll
            for (int am = 0; am < 2; ++am)
                #pragma unroll
                for (int bn = 0; bn < 2; ++bn)
                    acc[am][bn] = __builtin_amdgcn_mfma_f32_32x32x16_bf16(
                        af[am], bf[bn], acc[am][bn], 0, 0, 0);
        }
    }

    float bb[2];
    #pragma unroll
    for (int bn = 0; bn < 2; ++bn) bb[bn] = biasL[wx*64 + bn*32 + m];
    #pragma unroll
    for (int am = 0; am < 2; ++am)
        #pragma unroll
        for (int bn = 0; bn < 2; ++bn)
            #pragma unroll
            for (int r = 0; r < 16; ++r) {
                int row = i0 + wy*64 + am*32 + (r & 3) + 8*(r >> 2) + 4*hh;
                outL[(size_t)row*HH + wx*64 + bn*32 + m] = f2bf(acc[am][bn][r] + bb[bn]);
            }
}

// Fused QKV over contiguous 2304x768 bf16 weights; 768%128==0 -> one output each.
__global__ __launch_bounds__(256) void gemm_gld_qkv(
    const u16* __restrict__ Xb, const u16* __restrict__ Wb3,
    const float* __restrict__ bq, const float* __restrict__ bk, const float* __restrict__ bv,
    u16* __restrict__ oq, u16* __restrict__ ok, u16* __restrict__ ov)
{
    const int j0 = blockIdx.x * 128;
    const int sel = j0 / HH;
    const int lj = j0 - sel * HH;
    const float* bias = (sel == 0) ? bq : (sel == 1) ? bk : bv;
    u16* out = (sel == 0) ? oq : (sel == 1) ? ok : ov;
    gemm_gld_body(Xb, Wb3 + (size_t)j0 * HH, bias + lj, out + lj, blockIdx.y * 128);
}

__global__ __launch_bounds__(256) void gemm_gld_single(
    const u16* __restrict__ Xb, const u16* __restrict__ Wb,
    const float* __restrict__ bias, u16* __restrict__ out)
{
    const int j0 = blockIdx.x * 128;
    gemm_gld_body(Xb, Wb + (size_t)j0 * HH, bias + j0, out + j0, blockIdx.y * 128);
}

// Fallback (small ws): W fp32, cvt during staging — round-6 proven 16x16x32 kernel.
__global__ __launch_bounds__(256) void gemm_mfma_nt(
    const u16* __restrict__ Xb, const float* __restrict__ W,
    const float* __restrict__ bias, u16* __restrict__ out)
{
    __shared__ u16 Xs[128][40];
    __shared__ u16 Wt[64][40];
    const int t = threadIdx.x;
    const int w = t >> 6, lane = t & 63;
    const int c = lane & 15, qd = lane >> 4;
    const int i0 = blockIdx.y * 128, j0 = blockIdx.x * 64;
    const int xrow = t >> 1, xoff = (t & 1) * 16;
    const int wn = t >> 2, woff = (t & 3) * 8;

    floatx4 acc[2][4];
    #pragma unroll
    for (int mt = 0; mt < 2; ++mt)
        #pragma unroll
        for (int nt = 0; nt < 4; ++nt) acc[mt][nt] = (floatx4){0.f,0.f,0.f,0.f};

    for (int k0 = 0; k0 < HH; k0 += 32) {
        uint4 xa  = *(const uint4*)(Xb + (size_t)(i0 + xrow)*HH + k0 + xoff);
        uint4 xb2 = *(const uint4*)(Xb + (size_t)(i0 + xrow)*HH + k0 + xoff + 8);
        float4 wa = *(const float4*)(W + (size_t)(j0 + wn)*HH + k0 + woff);
        float4 wb = *(const float4*)(W + (size_t)(j0 + wn)*HH + k0 + woff + 4);
        __syncthreads();
        *(uint4*)&Xs[xrow][xoff]     = xa;
        *(uint4*)&Xs[xrow][xoff + 8] = xb2;
        ushort4 w0, w1;
        w0.x = f2bf(wa.x); w0.y = f2bf(wa.y); w0.z = f2bf(wa.z); w0.w = f2bf(wa.w);
        w1.x = f2bf(wb.x); w1.y = f2bf(wb.y); w1.z = f2bf(wb.z); w1.w = f2bf(wb.w);
        *(ushort4*)&Wt[wn][woff]     = w0;
        *(ushort4*)&Wt[wn][woff + 4] = w1;
        __syncthreads();

        short8 a0 = *(const short8*)&Xs[w*32 + c][qd*8];
        short8 a1 = *(const short8*)&Xs[w*32 + 16 + c][qd*8];
        #pragma unroll
        for (int nt = 0; nt < 4; ++nt) {
            short8 bfr = *(const short8*)&Wt[nt*16 + c][qd*8];
            acc[0][nt] = __builtin_amdgcn_mfma_f32_16x16x32_bf16(a0, bfr, acc[0][nt], 0, 0, 0);
            acc[1][nt] = __builtin_amdgcn_mfma_f32_16x16x32_bf16(a1, bfr, acc[1][nt], 0, 0, 0);
        }
    }

    float bv[4];
    #pragma unroll
    for (int nt = 0; nt < 4; ++nt) bv[nt] = bias[j0 + nt*16 + c];
    #pragma unroll
    for (int mt = 0; mt < 2; ++mt)
        #pragma unroll
        for (int nt = 0; nt < 4; ++nt)
            #pragma unroll
            for (int r = 0; r < 4; ++r)
                out[(size_t)(i0 + w*32 + mt*16 + qd*4 + r)*HH + j0 + nt*16 + c] =
                    f2bf(acc[mt][nt][r] + bv[nt]);
}

// MFMA flash attention — unchanged from round 9 (verified, 97 µs).
__global__ __launch_bounds__(256, 3) void attn_mfma(
    const u16* __restrict__ Q, const u16* __restrict__ K, const u16* __restrict__ V,
    const float* __restrict__ dim_biases, const int* __restrict__ mask,
    const int* __restrict__ dim_idx_p, u16* __restrict__ ctx)
{
    __shared__ u16 Ks[64][72];           // [key][d]
    __shared__ unsigned int Vt2[64][36]; // [d][keypair] packed 2 keys/uint
    __shared__ u16 Pt[4][2][16][72];     // [wave][group][q][key]  wave-private
    __shared__ float madd[64];

    const int t = threadIdx.x;
    const int w = t >> 6, lane = t & 63;
    const int c = lane & 15, qd = lane >> 4;
    const int b = blockIdx.z, h = blockIdx.y;
    const int q0 = blockIdx.x * 128;

    const int didx = *dim_idx_p;
    const float db2 = ((didx < NDIMS) ? dim_biases[didx*NHEAD + h] : 0.f) * LOG2E;

    short8 ones;
    #pragma unroll
    for (int j = 0; j < 8; ++j) ones[j] = (short)0x3F80;   // bf16 1.0

    short8 qf[2][2];
    #pragma unroll
    for (int g = 0; g < 2; ++g) {
        const u16* qsrc = Q + ((size_t)(b*SS + q0 + w*32 + g*16 + c))*HH + h*HDIM;
        #pragma unroll
        for (int kc = 0; kc < 2; ++kc) {
            ushort4 u0 = *(const ushort4*)(qsrc + kc*32 + qd*8);
            ushort4 u1 = *(const ushort4*)(qsrc + kc*32 + qd*8 + 4);
            const u16 uu[8] = {u0.x,u0.y,u0.z,u0.w,u1.x,u1.y,u1.z,u1.w};
            #pragma unroll
            for (int j = 0; j < 8; ++j)
                qf[g][kc][j] = (short)f2bf(bf2f(uu[j]) * QSCALE);
        }
    }

    floatx4 o[2][4], lacc[2];
    #pragma unroll
    for (int g = 0; g < 2; ++g) {
        lacc[g] = (floatx4){0.f,0.f,0.f,0.f};
        #pragma unroll
        for (int dt = 0; dt < 4; ++dt) o[g][dt] = (floatx4){0.f,0.f,0.f,0.f};
    }

    const int skey = t >> 2, sdp = (t & 3) * 16;
    const int vkp = t & 31, vdg = (t >> 5) * 8;

    for (int kt = 0; kt < SS/64; ++kt) {
        __syncthreads();
        {
            const u16* ksrc = K + ((size_t)(b*SS + kt*64 + skey))*HH + h*HDIM + sdp;
            *(uint4*)&Ks[skey][sdp]     = *(const uint4*)ksrc;
            *(uint4*)&Ks[skey][sdp + 8] = *(const uint4*)(ksrc + 8);
            const u16* va = V + ((size_t)(b*SS + kt*64 + 2*vkp))*HH + h*HDIM + vdg;
            const u16* vb = va + HH;
            ushort4 a0 = *(const ushort4*)va;
            ushort4 a1 = *(const ushort4*)(va + 4);
            ushort4 b0 = *(const ushort4*)vb;
            ushort4 b1 = *(const ushort4*)(vb + 4);
            const u16 aa[8] = {a0.x,a0.y,a0.z,a0.w,a1.x,a1.y,a1.z,a1.w};
            const u16 bb[8] = {b0.x,b0.y,b0.z,b0.w,b1.x,b1.y,b1.z,b1.w};
            #pragma unroll
            for (int i = 0; i < 8; ++i)
                Vt2[vdg + i][vkp] = (unsigned int)aa[i] | ((unsigned int)bb[i] << 16);
            if (t < 64)
                madd[t] = (mask[(size_t)b*SS + kt*64 + t] != 0) ? db2 : -1e30f;
        }
        __syncthreads();

        floatx4 z[2][4];
        {
            short8 ka[4][2];
            #pragma unroll
            for (int mt = 0; mt < 4; ++mt) {
                ka[mt][0] = *(const short8*)&Ks[mt*16 + c][qd*8];
                ka[mt][1] = *(const short8*)&Ks[mt*16 + c][32 + qd*8];
            }
            #pragma unroll
            for (int g = 0; g < 2; ++g)
                #pragma unroll
                for (int mt = 0; mt < 4; ++mt) {
                    floatx4 zz = __builtin_amdgcn_mfma_f32_16x16x32_bf16(ka[mt][0], qf[g][0], (floatx4){0.f,0.f,0.f,0.f}, 0, 0, 0);
                    z[g][mt] = __builtin_amdgcn_mfma_f32_16x16x32_bf16(ka[mt][1], qf[g][1], zz, 0, 0, 0);
                }
        }

        #pragma unroll
        for (int g = 0; g < 2; ++g) {
            #pragma unroll
            for (int mt = 0; mt < 4; ++mt) {
                unsigned int pk[2];
                #pragma unroll
                for (int half = 0; half < 2; ++half) {
                    float p0 = __builtin_amdgcn_exp2f(z[g][mt][half*2]     + madd[mt*16 + qd*4 + half*2]);
                    float p1 = __builtin_amdgcn_exp2f(z[g][mt][half*2 + 1] + madd[mt*16 + qd*4 + half*2 + 1]);
                    pk[half] = pack_bf16x2(p0, p1);
                }
                *(uint2*)&Pt[w][g][c][mt*16 + qd*4] = make_uint2(pk[0], pk[1]);
            }
        }

        {
            short8 vt[2][4];
            #pragma unroll
            for (int kc = 0; kc < 2; ++kc)
                #pragma unroll
                for (int dt = 0; dt < 4; ++dt)
                    vt[kc][dt] = *(const short8*)&Vt2[dt*16 + c][kc*16 + qd*4];
            #pragma unroll
            for (int g = 0; g < 2; ++g)
                #pragma unroll
                for (int kc = 0; kc < 2; ++kc) {
                    short8 ap = *(const short8*)&Pt[w][g][c][kc*32 + qd*8];
                    lacc[g] = __builtin_amdgcn_mfma_f32_16x16x32_bf16(ap, ones, lacc[g], 0, 0, 0);
                    #pragma unroll
                    for (int dt = 0; dt < 4; ++dt)
                        o[g][dt] = __builtin_amdgcn_mfma_f32_16x16x32_bf16(ap, vt[kc][dt], o[g][dt], 0, 0, 0);
                }
        }
    }

    #pragma unroll
    for (int g = 0; g < 2; ++g) {
        #pragma unroll
        for (int r = 0; r < 4; ++r) {
            float lr = lacc[g][r];
            float inv = (lr > 0.f) ? 1.f / lr : 0.f;
            u16* dst = ctx + ((size_t)(b*SS + q0 + w*32 + g*16 + qd*4 + r))*HH + h*HDIM + c;
            #pragma unroll
            for (int dt = 0; dt < 4; ++dt)
                dst[dt*16] = f2bf(o[g][dt][r] * inv);
        }
    }
}

// Wave-per-row LN: 4 rows/block, lane handles 12 contiguous elements.
__global__ __launch_bounds__(256) void add_ln_wave(
    const u16* __restrict__ proj, const float* __restrict__ resid,
    const float* __restrict__ gamma, const float* __restrict__ beta,
    float* __restrict__ out)
{
    const int t = threadIdx.x, w = t >> 6, lane = t & 63;
    const int row = blockIdx.x * 4 + w;
    const size_t base = (size_t)row * HH + lane * 12;
    const int gbase = lane * 12;

    float x[12];
    #pragma unroll
    for (int j = 0; j < 3; ++j) {
        ushort4 p = *(const ushort4*)(proj + base + j*4);
        float4  r = *(const float4*)(resid + base + j*4);
        x[j*4+0] = bf2f(p.x) + r.x;
        x[j*4+1] = bf2f(p.y) + r.y;
        x[j*4+2] = bf2f(p.z) + r.z;
        x[j*4+3] = bf2f(p.w) + r.w;
    }
    float s = 0.f, ss = 0.f;
    #pragma unroll
    for (int j = 0; j < 12; ++j) { s += x[j]; ss += x[j]*x[j]; }
    #pragma unroll
    for (int off = 1; off < 64; off <<= 1) {
        s  += __shfl_xor(s, off);
        ss += __shfl_xor(ss, off);
    }
    float mean = s * (1.f/768.f);
    float var  = ss * (1.f/768.f) - mean*mean;
    float rstd = rsqrtf(fmaxf(var, 0.f) + 1e-5f);
    #pragma unroll
    for (int j = 0; j < 3; ++j) {
        float4 g = *(const float4*)(gamma + gbase + j*4);
        float4 bt = *(const float4*)(beta + gbase + j*4);
        float4 y;
        y.x = (x[j*4+0]-mean)*rstd*g.x + bt.x;
        y.y = (x[j*4+1]-mean)*rstd*g.y + bt.y;
        y.z = (x[j*4+2]-mean)*rstd*g.z + bt.z;
        y.w = (x[j*4+3]-mean)*rstd*g.w + bt.w;
        *(float4*)(out + base + j*4) = y;
    }
}

extern "C" void kernel_launch(void* const* d_in, const int* in_sizes, int n_in,
                              void* d_out, int out_size, void* d_ws, size_t ws_size,
                              hipStream_t stream)
{
    (void)in_sizes; (void)n_in; (void)out_size;
    const float* x    = (const float*)d_in[0];
    const float* Wq   = (const float*)d_in[1];
    const float* bq   = (const float*)d_in[2];
    const float* Wk   = (const float*)d_in[3];
    const float* bk   = (const float*)d_in[4];
    const float* Wv   = (const float*)d_in[5];
    const float* bv   = (const float*)d_in[6];
    const float* Wo   = (const float*)d_in[7];
    const float* bo   = (const float*)d_in[8];
    const float* dimb = (const float*)d_in[9];
    const float* gam  = (const float*)d_in[10];
    const float* bet  = (const float*)d_in[11];
    const int* mask   = (const int*)d_in[12];
    const int* didx   = (const int*)d_in[13];

    const size_t N = (size_t)MM * HH;            // 6,291,456 elements
    if (ws_size < 4 * N * sizeof(u16)) return;   // 50.3 MB, proven
    u16* ws = (u16*)d_ws;
    u16* q    = ws;          // slot0: q, later proj
    u16* kbuf = ws + N;      // slot1
    u16* vbuf = ws + 2*N;    // slot2
    u16* slot3 = ws + 3*N;   // xb during QKV GEMMs, then ctx
    u16* xb   = slot3;
    u16* ctx  = slot3;
    u16* proj = q;

    const bool bigws = ws_size >= (4 * N + 4 * (size_t)WEL) * sizeof(u16);  // +4.7 MB
    u16* wb = ws + 4 * N;    // bf16 weights, contiguous (Wq;Wk;Wv;Wo) = 3072x768

    f32_to_bf16<<<(int)(N/8/256), 256, 0, stream>>>(x, xb, (int)(N/8));
    if (bigws) {
        w_cvt4<<<dim3(WEL/8/256, 4), 256, 0, stream>>>(Wq, Wk, Wv, Wo, wb);
        gemm_gld_qkv<<<dim3(3*HH/128, MM/128), 256, 0, stream>>>(
            xb, wb, bq, bk, bv, q, kbuf, vbuf);
    } else {
        dim3 gg(HH/64, MM/128);
        gemm_mfma_nt<<<gg, 256, 0, stream>>>(xb, Wq, bq, q);
        gemm_mfma_nt<<<gg, 256, 0, stream>>>(xb, Wk, bk, kbuf);
        gemm_mfma_nt<<<gg, 256, 0, stream>>>(xb, Wv, bv, vbuf);
    }
    attn_mfma<<<dim3(SS/128, NHEAD, BB), 256, 0, stream>>>(q, kbuf, vbuf, dimb, mask, didx, ctx);
    if (bigws) gemm_gld_single<<<dim3(HH/128, MM/128), 256, 0, stream>>>(ctx, wb + 3*WEL, bo, proj);
    else {
        dim3 gg(HH/64, MM/128);
        gemm_mfma_nt<<<gg, 256, 0, stream>>>(ctx, Wo, bo, proj);
    }
    add_ln_wave<<<MM/4, 256, 0, stream>>>(proj, x, gam, bet, (float*)d_out);
}